// Round 2
// baseline (297.681 us; speedup 1.0000x reference)
//
#include <hip/hip_runtime.h>
#include <hip/hip_bf16.h>

// Problem constants: G=64, C=32, L=128, D=64, H=128, NCLS=10
#define NSEQ 2048   // G*C
#define LSEQ 128
#define DIN  64
#define HID  128
#define NCLS 10

typedef __attribute__((ext_vector_type(8))) short bfrag8;   // 8 bf16 = 4 VGPRs (MFMA A/B frag)
typedef __attribute__((ext_vector_type(4))) float facc4;    // MFMA C/D frag

__device__ __forceinline__ short f2bf(float f) {
    union { __hip_bfloat16 b; short s; } u;
    u.b = __float2bfloat16(f);   // RNE
    return u.s;
}

// Load 8 consecutive f32 and round to a bf16 MFMA fragment (short8).
__device__ __forceinline__ bfrag8 load_bf16_frag(const float* __restrict__ p) {
    bfrag8 r;
#pragma unroll
    for (int j = 0; j < 8; ++j) r[j] = f2bf(p[j]);
    return r;
}

__device__ __forceinline__ float fast_sigmoid(float x) {
    // 1/(1+exp(-x)) — NaN-safe for all finite x (exp2 saturates to 0/inf)
    float e = __builtin_amdgcn_exp2f(-1.4426950408889634f * x);
    return __builtin_amdgcn_rcpf(1.0f + e);
}
__device__ __forceinline__ float fast_tanh(float x) {
    // 1 - 2/(1+exp(2x)) — saturates correctly at +/-1
    float e = __builtin_amdgcn_exp2f(2.8853900817779268f * x);
    return 1.0f - 2.0f * __builtin_amdgcn_rcpf(1.0f + e);
}

// One block = 8 sequences (padded to M=16), 8 waves.
// Wave w owns gate columns {g*128 + w*16 .. +15} for g in {i,f,g,o} ->
// each lane's four C-frags are exactly i,f,g,o of its 16 hidden units,
// so gates never touch LDS; c-state/h-sum stay in registers.
__global__ __launch_bounds__(512) void lstm_fused(
    const float* __restrict__ x,      // [2048][128][64] f32
    const float* __restrict__ Wih,    // [512][64] f32
    const float* __restrict__ Whh,    // [512][128] f32
    const float* __restrict__ bih,    // [512] f32
    const float* __restrict__ bhh,    // [512] f32
    float* __restrict__ rep)          // [2048][128] f32 (d_ws)
{
    // h double-buffer: row stride 136 bf16 = 272B -> conflict-free ds_read_b128
    __shared__ __align__(16) __hip_bfloat16 hbuf[2][16][136];

    const int tid  = threadIdx.x;
    const int w    = tid >> 6;        // wave 0..7
    const int lane = tid & 63;
    const int ln   = lane & 15;
    const int qd   = lane >> 4;
    const int s0   = blockIdx.x * 8;  // first sequence of this block
    const int khid = w * 16 + ln;     // hidden unit index this lane covers

    // ---- weight B-fragments: f32 load -> bf16 registers (reused all 128 steps) ----
    // B-frag for W^T: lane (n=ln, q=qd) holds B[k0*32 + qd*8 + j][n] = W[col][k0*32+qd*8+j].
    bfrag8 whh[4][4];   // [gate][k-step], K=128
    bfrag8 wih[4][2];   // [gate][k-step], K=64
    float  biasv[4];
#pragma unroll
    for (int g = 0; g < 4; ++g) {
        const int col = g * HID + khid;             // gate row in [0,512)
        biasv[g] = bih[col] + bhh[col];
#pragma unroll
        for (int k0 = 0; k0 < 4; ++k0)
            whh[g][k0] = load_bf16_frag(Whh + col * HID + k0 * 32 + qd * 8);
#pragma unroll
        for (int k0 = 0; k0 < 2; ++k0)
            wih[g][k0] = load_bf16_frag(Wih + col * DIN + k0 * 32 + qd * 8);
    }

    // zero both h buffers (rows 8..15 stay zero forever -> padded M rows read 0)
    {
        unsigned int* p = (unsigned int*)&hbuf[0][0][0];
        for (int i = tid; i < 2 * 16 * 136 / 2; i += 512) p[i] = 0u;
    }

    // x A-frag: A[m=lane&15][k=qd*8+j]; padded rows 8-15 mirror rows 0-7 (discarded)
    const float* xptr = x + (size_t)(s0 + (ln & 7)) * (LSEQ * DIN) + qd * 8;

    float cst[4]  = {0.f, 0.f, 0.f, 0.f};   // c for rows s = qd*4+r (valid on qd<2)
    float hsum[4] = {0.f, 0.f, 0.f, 0.f};

    bfrag8 xf[2];
#pragma unroll
    for (int k0 = 0; k0 < 2; ++k0)
        xf[k0] = load_bf16_frag(xptr + k0 * 32);

    __syncthreads();

    int cur = 0;
    for (int t = 0; t < LSEQ; ++t) {
        // h A-frags from LDS (double-buffered -> single barrier per step suffices)
        bfrag8 hf[4];
#pragma unroll
        for (int k0 = 0; k0 < 4; ++k0)
            hf[k0] = *(const bfrag8*)(&hbuf[cur][ln][k0 * 32 + qd * 8]);

        // prefetch + convert x for next step
        bfrag8 xn[2];
        {
            const int tn = (t < LSEQ - 1) ? (t + 1) : t;
#pragma unroll
            for (int k0 = 0; k0 < 2; ++k0)
                xn[k0] = load_bf16_frag(xptr + tn * DIN + k0 * 32);
        }

        // gates = bias + x_t @ Wih^T + h_t @ Whh^T
        facc4 acc[4];
#pragma unroll
        for (int g = 0; g < 4; ++g)
            acc[g] = (facc4){biasv[g], biasv[g], biasv[g], biasv[g]};
#pragma unroll
        for (int g = 0; g < 4; ++g)
#pragma unroll
            for (int k0 = 0; k0 < 2; ++k0)
                acc[g] = __builtin_amdgcn_mfma_f32_16x16x32_bf16(xf[k0], wih[g][k0], acc[g], 0, 0, 0);
#pragma unroll
        for (int g = 0; g < 4; ++g)
#pragma unroll
            for (int k0 = 0; k0 < 4; ++k0)
                acc[g] = __builtin_amdgcn_mfma_f32_16x16x32_bf16(hf[k0], whh[g][k0], acc[g], 0, 0, 0);

        // elementwise LSTM cell: C/D frag row = qd*4 + r (= sequence), col = lane&15 (= hidden)
        short hb[4];
#pragma unroll
        for (int r = 0; r < 4; ++r) {
            float iv = fast_sigmoid(acc[0][r]);
            float fv = fast_sigmoid(acc[1][r]);
            float gv = fast_tanh(acc[2][r]);
            float ov = fast_sigmoid(acc[3][r]);
            float c  = fv * cst[r] + iv * gv;
            cst[r]   = c;
            float hv = ov * fast_tanh(c);
            hsum[r] += hv;                 // accumulate pre-rounding (f32)
            hb[r]    = f2bf(hv);
        }

        // write h_{t+1} into the other buffer (only valid rows 0..7 -> quads 0,1)
        if (qd < 2) {
#pragma unroll
            for (int r = 0; r < 4; ++r)
                ((short*)&hbuf[cur ^ 1][qd * 4 + r][0])[khid] = hb[r];
        }
        xf[0] = xn[0]; xf[1] = xn[1];
        __syncthreads();    // single barrier per step (double-buffered h)
        cur ^= 1;
    }

    // rep[b][k] = sum_t h_t[b][k]
    if (qd < 2) {
#pragma unroll
        for (int r = 0; r < 4; ++r)
            rep[(size_t)(s0 + qd * 4 + r) * HID + khid] = hsum[r];
    }
}

// Epilogue: graph mean over C=32, classifier [10,128], log-softmax -> f32 out[64][10]
__global__ __launch_bounds__(128) void cls_kernel(
    const float* __restrict__ rep,    // [2048][128]
    const float* __restrict__ Wcls,   // [10][128]
    const float* __restrict__ bcls,   // [10]
    float* __restrict__ out)          // [64][10]
{
    __shared__ float m_s[HID];
    __shared__ float logits_s[NCLS];
    const int g = blockIdx.x;
    const int h = threadIdx.x;

    float s = 0.f;
#pragma unroll 4
    for (int c = 0; c < 32; ++c)
        s += rep[((size_t)g * 32 + c) * HID + h];
    m_s[h] = s * (1.0f / 32.0f);
    __syncthreads();

    if (h < NCLS) {
        float acc = bcls[h];
        for (int k = 0; k < HID; ++k)
            acc += m_s[k] * Wcls[h * HID + k];
        logits_s[h] = acc;
    }
    __syncthreads();

    if (h < NCLS) {
        float mx = logits_s[0];
#pragma unroll
        for (int j = 1; j < NCLS; ++j) mx = fmaxf(mx, logits_s[j]);
        float se = 0.f;
#pragma unroll
        for (int j = 0; j < NCLS; ++j)
            se += __builtin_amdgcn_exp2f((logits_s[j] - mx) * 1.4426950408889634f);
        // v_log_f32 is log2 -> ln(se) = ln2 * log2(se)
        float lse = mx + 0.6931471805599453f * __builtin_amdgcn_logf(se);
        out[g * NCLS + h] = logits_s[h] - lse;
    }
}

extern "C" void kernel_launch(void* const* d_in, const int* in_sizes, int n_in,
                              void* d_out, int out_size, void* d_ws, size_t ws_size,
                              hipStream_t stream) {
    const float* x    = (const float*)d_in[0];
    const float* Wih  = (const float*)d_in[1];
    const float* Whh  = (const float*)d_in[2];
    const float* bih  = (const float*)d_in[3];
    const float* bhh  = (const float*)d_in[4];
    const float* Wcls = (const float*)d_in[5];
    const float* bcls = (const float*)d_in[6];

    float* rep = (float*)d_ws;   // 2048*128 fp32 = 1 MB scratch

    lstm_fused<<<NSEQ / 8, 512, 0, stream>>>(x, Wih, Whh, bih, bhh, rep);
    cls_kernel<<<64, 128, 0, stream>>>(rep, Wcls, bcls, (float*)d_out);
}

// Round 3
// 231.115 us; speedup vs baseline: 1.2880x; 1.2880x over previous
//
#include <hip/hip_runtime.h>
#include <hip/hip_bf16.h>

// Problem constants: G=64, C=32, L=128, D=64, H=128, NCLS=10
#define NSEQ 2048   // G*C
#define LSEQ 128
#define DIN  64
#define HID  128
#define NCLS 10
#define XPAD 72     // padded x row (shorts): start bank = 4*((ln&7)+qd)+16k -> even spread
#define CHK  16     // timesteps staged per chunk

typedef __attribute__((ext_vector_type(8))) short bfrag8;   // 8 bf16 = 4 VGPRs (MFMA A/B frag)
typedef __attribute__((ext_vector_type(4))) float facc4;    // MFMA C/D frag

__device__ __forceinline__ short f2bf(float f) {
    union { __hip_bfloat16 b; short s; } u;
    u.b = __float2bfloat16(f);   // RNE
    return u.s;
}

__device__ __forceinline__ bfrag8 load_bf16_frag(const float* __restrict__ p) {
    bfrag8 r;
#pragma unroll
    for (int j = 0; j < 8; ++j) r[j] = f2bf(p[j]);
    return r;
}

__device__ __forceinline__ float fast_sigmoid(float x) {
    float e = __builtin_amdgcn_exp2f(-1.4426950408889634f * x);
    return __builtin_amdgcn_rcpf(1.0f + e);
}
__device__ __forceinline__ float fast_tanh(float x) {
    float e = __builtin_amdgcn_exp2f(2.8853900817779268f * x);
    return 1.0f - 2.0f * __builtin_amdgcn_rcpf(1.0f + e);
}

// One block = 8 sequences (padded to M=16), 8 waves. Wave w owns gate columns
// {g*128 + w*16} for g in {i,f,g,o} -> lane's 4 C-frags are i,f,g,o of its 16
// hidden units; c-state/h-sum stay in registers. Steady-state loop touches LDS
// only; x is staged to LDS as bf16 in double-buffered 16-step chunks.
__global__ __launch_bounds__(512) void lstm_fused(
    const float* __restrict__ x,      // [2048][128][64] f32
    const float* __restrict__ Wih,    // [512][64] f32
    const float* __restrict__ Whh,    // [512][128] f32
    const float* __restrict__ bih,    // [512] f32
    const float* __restrict__ bhh,    // [512] f32
    float* __restrict__ rep)          // [2048][128] f32 (d_ws)
{
    // h double-buffer: row stride 136 bf16 = 272B -> even-bank ds_read_b128
    __shared__ __align__(16) __hip_bfloat16 hbuf[2][16][136];          // 8704 B
    __shared__ __align__(16) __hip_bfloat16 xs[2][CHK][8][XPAD];       // 36864 B

    const int tid  = threadIdx.x;
    const int w    = tid >> 6;        // wave 0..7
    const int lane = tid & 63;
    const int ln   = lane & 15;
    const int qd   = lane >> 4;
    const int s0   = blockIdx.x * 8;  // first sequence of this block
    const int khid = w * 16 + ln;     // hidden unit index this lane covers

    // ---- weight B-fragments: f32 -> bf16 registers (reused all 128 steps) ----
    bfrag8 whh[4][4];   // [gate][k-step], K=128
    bfrag8 wih[4][2];   // [gate][k-step], K=64
    float  biasv[4];
#pragma unroll
    for (int g = 0; g < 4; ++g) {
        const int col = g * HID + khid;             // gate row in [0,512)
        biasv[g] = bih[col] + bhh[col];
#pragma unroll
        for (int k0 = 0; k0 < 4; ++k0)
            whh[g][k0] = load_bf16_frag(Whh + col * HID + k0 * 32 + qd * 8);
#pragma unroll
        for (int k0 = 0; k0 < 2; ++k0)
            wih[g][k0] = load_bf16_frag(Wih + col * DIN + k0 * 32 + qd * 8);
    }

    // zero both h buffers (rows 8..15 stay zero -> padded M rows read 0)
    {
        unsigned int* p = (unsigned int*)&hbuf[0][0][0];
        for (int i = tid; i < 2 * 16 * 136 / 2; i += 512) p[i] = 0u;
    }

    // ---- x chunk staging plan: wave w stages sequence s0+w; lane covers 16
    // consecutive f32 (64B coalesced per wave). Element e = lane*16+j maps to
    // tt = e>>6, d = e&63 -> LDS xs[nb][tt][w][(lane&3)*16 .. +15].
    const float* xsrc = x + (size_t)(s0 + w) * (LSEQ * DIN) + lane * 16;
    const int stt = lane >> 2;          // timestep-in-chunk this lane stages
    const int sdd = (lane & 3) * 16;    // d-offset this lane stages

    // stage chunk 0 synchronously
    {
        float4 l0 = ((const float4*)xsrc)[0];
        float4 l1 = ((const float4*)xsrc)[1];
        float4 l2 = ((const float4*)xsrc)[2];
        float4 l3 = ((const float4*)xsrc)[3];
        bfrag8 o0, o1;
#pragma unroll
        for (int j = 0; j < 4; ++j) { o0[j] = f2bf(((float*)&l0)[j]); o0[4+j] = f2bf(((float*)&l1)[j]); }
#pragma unroll
        for (int j = 0; j < 4; ++j) { o1[j] = f2bf(((float*)&l2)[j]); o1[4+j] = f2bf(((float*)&l3)[j]); }
        *(bfrag8*)&xs[0][stt][w][sdd]     = o0;
        *(bfrag8*)&xs[0][stt][w][sdd + 8] = o1;
    }

    float cst[4]  = {0.f, 0.f, 0.f, 0.f};   // c for rows qd*4+r (valid on qd<2)
    float hsum[4] = {0.f, 0.f, 0.f, 0.f};

    __syncthreads();

    int cur = 0;
    for (int chunk = 0; chunk < LSEQ / CHK; ++chunk) {
        const int buf = chunk & 1;
        const bool more = chunk < (LSEQ / CHK - 1);
        float4 l0, l1, l2, l3;
#pragma unroll 1
        for (int ct = 0; ct < CHK; ++ct) {
            // h A-frags from LDS (double-buffered)
            bfrag8 hf[4];
#pragma unroll
            for (int k0 = 0; k0 < 4; ++k0)
                hf[k0] = *(const bfrag8*)(&hbuf[cur][ln][k0 * 32 + qd * 8]);
            // x A-frags from LDS chunk buffer
            bfrag8 xf0 = *(const bfrag8*)(&xs[buf][ct][ln & 7][qd * 8]);
            bfrag8 xf1 = *(const bfrag8*)(&xs[buf][ct][ln & 7][32 + qd * 8]);

            if (ct == 0 && more) {      // issue next chunk's global loads
                const float* p = xsrc + (chunk + 1) * (CHK * DIN);
                l0 = ((const float4*)p)[0];
                l1 = ((const float4*)p)[1];
                l2 = ((const float4*)p)[2];
                l3 = ((const float4*)p)[3];
            }
            if (ct == 12 && more) {     // convert + write next chunk to LDS
                bfrag8 o0, o1;
#pragma unroll
                for (int j = 0; j < 4; ++j) { o0[j] = f2bf(((float*)&l0)[j]); o0[4+j] = f2bf(((float*)&l1)[j]); }
#pragma unroll
                for (int j = 0; j < 4; ++j) { o1[j] = f2bf(((float*)&l2)[j]); o1[4+j] = f2bf(((float*)&l3)[j]); }
                *(bfrag8*)&xs[buf ^ 1][stt][w][sdd]     = o0;
                *(bfrag8*)&xs[buf ^ 1][stt][w][sdd + 8] = o1;
            }

            // gates = bias + x_t @ Wih^T + h_t @ Whh^T
            facc4 acc[4];
#pragma unroll
            for (int g = 0; g < 4; ++g)
                acc[g] = (facc4){biasv[g], biasv[g], biasv[g], biasv[g]};
#pragma unroll
            for (int g = 0; g < 4; ++g) {
                acc[g] = __builtin_amdgcn_mfma_f32_16x16x32_bf16(xf0, wih[g][0], acc[g], 0, 0, 0);
                acc[g] = __builtin_amdgcn_mfma_f32_16x16x32_bf16(xf1, wih[g][1], acc[g], 0, 0, 0);
            }
#pragma unroll
            for (int g = 0; g < 4; ++g)
#pragma unroll
                for (int k0 = 0; k0 < 4; ++k0)
                    acc[g] = __builtin_amdgcn_mfma_f32_16x16x32_bf16(hf[k0], whh[g][k0], acc[g], 0, 0, 0);

            // LSTM cell: C/D row = qd*4 + r (= sequence), col = lane&15 (= hidden)
            short hb[4];
#pragma unroll
            for (int r = 0; r < 4; ++r) {
                float iv = fast_sigmoid(acc[0][r]);
                float fv = fast_sigmoid(acc[1][r]);
                float gv = fast_tanh(acc[2][r]);
                float ov = fast_sigmoid(acc[3][r]);
                float c  = fv * cst[r] + iv * gv;
                cst[r]   = c;
                float hv = ov * fast_tanh(c);
                hsum[r] += hv;                 // accumulate pre-rounding (f32)
                hb[r]    = f2bf(hv);
            }

            // write h_{t+1} into the other buffer (valid rows 0..7 -> quads 0,1)
            if (qd < 2) {
#pragma unroll
                for (int r = 0; r < 4; ++r)
                    ((short*)&hbuf[cur ^ 1][qd * 4 + r][0])[khid] = hb[r];
            }
            __syncthreads();    // single barrier per step (double-buffered h)
            cur ^= 1;
        }
    }

    // rep[b][k] = sum_t h_t[b][k]
    if (qd < 2) {
#pragma unroll
        for (int r = 0; r < 4; ++r)
            rep[(size_t)(s0 + qd * 4 + r) * HID + khid] = hsum[r];
    }
}

// Epilogue: graph mean over C=32, classifier [10,128], log-softmax -> f32 out[64][10]
__global__ __launch_bounds__(128) void cls_kernel(
    const float* __restrict__ rep,    // [2048][128]
    const float* __restrict__ Wcls,   // [10][128]
    const float* __restrict__ bcls,   // [10]
    float* __restrict__ out)          // [64][10]
{
    __shared__ float m_s[HID];
    __shared__ float logits_s[NCLS];
    const int g = blockIdx.x;
    const int h = threadIdx.x;

    float s = 0.f;
#pragma unroll 4
    for (int c = 0; c < 32; ++c)
        s += rep[((size_t)g * 32 + c) * HID + h];
    m_s[h] = s * (1.0f / 32.0f);
    __syncthreads();

    if (h < NCLS) {
        float acc = bcls[h];
        for (int k = 0; k < HID; ++k)
            acc += m_s[k] * Wcls[h * HID + k];
        logits_s[h] = acc;
    }
    __syncthreads();

    if (h < NCLS) {
        float mx = logits_s[0];
#pragma unroll
        for (int j = 1; j < NCLS; ++j) mx = fmaxf(mx, logits_s[j]);
        float se = 0.f;
#pragma unroll
        for (int j = 0; j < NCLS; ++j)
            se += __builtin_amdgcn_exp2f((logits_s[j] - mx) * 1.4426950408889634f);
        float lse = mx + 0.6931471805599453f * __builtin_amdgcn_logf(se);
        out[g * NCLS + h] = logits_s[h] - lse;
    }
}

extern "C" void kernel_launch(void* const* d_in, const int* in_sizes, int n_in,
                              void* d_out, int out_size, void* d_ws, size_t ws_size,
                              hipStream_t stream) {
    const float* x    = (const float*)d_in[0];
    const float* Wih  = (const float*)d_in[1];
    const float* Whh  = (const float*)d_in[2];
    const float* bih  = (const float*)d_in[3];
    const float* bhh  = (const float*)d_in[4];
    const float* Wcls = (const float*)d_in[5];
    const float* bcls = (const float*)d_in[6];

    float* rep = (float*)d_ws;   // 2048*128 fp32 = 1 MB scratch

    lstm_fused<<<NSEQ / 8, 512, 0, stream>>>(x, Wih, Whh, bih, bhh, rep);
    cls_kernel<<<64, 128, 0, stream>>>(rep, Wcls, bcls, (float*)d_out);
}

// Round 4
// 201.259 us; speedup vs baseline: 1.4791x; 1.1483x over previous
//
#include <hip/hip_runtime.h>
#include <hip/hip_bf16.h>

// Problem constants: G=64, C=32, L=128, D=64, H=128, NCLS=10
#define NSEQ 2048   // G*C
#define LSEQ 128
#define DIN  64
#define HID  128
#define NCLS 10
#define XPAD 72     // padded x row (shorts)
#define CHK  16     // timesteps staged per chunk

typedef __attribute__((ext_vector_type(8))) short bfrag8;   // 8 bf16 (MFMA A/B frag)
typedef __attribute__((ext_vector_type(4))) float facc4;    // MFMA C/D frag

__device__ __forceinline__ short f2bf(float f) {
    union { __hip_bfloat16 b; short s; } u;
    u.b = __float2bfloat16(f);   // RNE
    return u.s;
}

__device__ __forceinline__ bfrag8 load_bf16_frag(const float* __restrict__ p) {
    bfrag8 r;
#pragma unroll
    for (int j = 0; j < 8; ++j) r[j] = f2bf(p[j]);
    return r;
}

__device__ __forceinline__ float fast_sigmoid(float x) {
    float e = __builtin_amdgcn_exp2f(-1.4426950408889634f * x);
    return __builtin_amdgcn_rcpf(1.0f + e);
}
__device__ __forceinline__ float fast_tanh(float x) {
    float e = __builtin_amdgcn_exp2f(2.8853900817779268f * x);
    return 1.0f - 2.0f * __builtin_amdgcn_rcpf(1.0f + e);
}

// One block = 8 sequences (M=16 padded), 8 waves; wave w owns gate columns
// {g*128 + w*16} -> lane's 4 C-frags are i,f,g,o of its 16 hidden units.
// After MFMA, regs r2,r3 are exchanged across the 32-lane halves so all 64
// lanes get 2 VALID cell-units (seq map: qd0:{0,1} qd1:{4,5} qd2:{2,3}
// qd3:{6,7}) -> cell VALU halves vs computing padded rows.
// x(t+1) MFMAs + reads issue during step t's cell phase (h-independent).
__global__ __launch_bounds__(512) void lstm_fused(
    const float* __restrict__ x,      // [2048][128][64] f32
    const float* __restrict__ Wih,    // [512][64] f32
    const float* __restrict__ Whh,    // [512][128] f32
    const float* __restrict__ bih,    // [512] f32
    const float* __restrict__ bhh,    // [512] f32
    float* __restrict__ rep)          // [2048][128] f32 (d_ws)
{
    __shared__ __align__(16) __hip_bfloat16 hbuf[2][16][136];          // 8704 B
    __shared__ __align__(16) __hip_bfloat16 xs[2][CHK][8][XPAD];       // 36864 B

    const int tid  = threadIdx.x;
    const int w    = tid >> 6;
    const int lane = tid & 63;
    const int ln   = lane & 15;
    const int qd   = lane >> 4;
    const int s0   = blockIdx.x * 8;
    const int khid = w * 16 + ln;
    // this lane's two assigned sequences after the r2/r3 half-exchange
    const int sq0  = (qd & 1) * 4 + (qd >> 1) * 2;   // {0,4,2,6}
    const int sq1  = sq0 + 1;                        // {1,5,3,7}
    const bool hi  = (qd >= 2);

    // ---- weight B-fragments: f32 -> bf16 registers (reused all 128 steps) ----
    bfrag8 whh[4][4];
    bfrag8 wih[4][2];
    float  biasv[4];
#pragma unroll
    for (int g = 0; g < 4; ++g) {
        const int col = g * HID + khid;
        biasv[g] = bih[col] + bhh[col];
#pragma unroll
        for (int k0 = 0; k0 < 4; ++k0)
            whh[g][k0] = load_bf16_frag(Whh + col * HID + k0 * 32 + qd * 8);
#pragma unroll
        for (int k0 = 0; k0 < 2; ++k0)
            wih[g][k0] = load_bf16_frag(Wih + col * DIN + k0 * 32 + qd * 8);
    }

    // zero both h buffers (rows 8..15 stay zero -> padded M rows read 0)
    {
        unsigned int* p = (unsigned int*)&hbuf[0][0][0];
        for (int i = tid; i < 2 * 16 * 136 / 2; i += 512) p[i] = 0u;
    }

    // x staging: wave w stages sequence s0+w; lane covers 16 consecutive f32.
    const float* xsrc = x + (size_t)(s0 + w) * (LSEQ * DIN) + lane * 16;
    const int stt = lane >> 2;
    const int sdd = (lane & 3) * 16;

    {   // stage chunk 0
        float4 a0 = ((const float4*)xsrc)[0];
        float4 a1 = ((const float4*)xsrc)[1];
        float4 a2 = ((const float4*)xsrc)[2];
        float4 a3 = ((const float4*)xsrc)[3];
        bfrag8 o0, o1;
#pragma unroll
        for (int j = 0; j < 4; ++j) { o0[j] = f2bf(((float*)&a0)[j]); o0[4+j] = f2bf(((float*)&a1)[j]); }
#pragma unroll
        for (int j = 0; j < 4; ++j) { o1[j] = f2bf(((float*)&a2)[j]); o1[4+j] = f2bf(((float*)&a3)[j]); }
        *(bfrag8*)&xs[0][stt][w][sdd]     = o0;
        *(bfrag8*)&xs[0][stt][w][sdd + 8] = o1;
    }

    float cst[2]  = {0.f, 0.f};
    float hsum[2] = {0.f, 0.f};

    __syncthreads();

    // prologue: acc for t=0 = bias + x(0) @ Wih^T
    facc4 accA[4], accB[4];
    {
        bfrag8 x0 = *(const bfrag8*)(&xs[0][0][ln & 7][qd * 8]);
        bfrag8 x1 = *(const bfrag8*)(&xs[0][0][ln & 7][32 + qd * 8]);
#pragma unroll
        for (int g = 0; g < 4; ++g) {
            accA[g] = (facc4){biasv[g], biasv[g], biasv[g], biasv[g]};
            accA[g] = __builtin_amdgcn_mfma_f32_16x16x32_bf16(x0, wih[g][0], accA[g], 0, 0, 0);
            accA[g] = __builtin_amdgcn_mfma_f32_16x16x32_bf16(x1, wih[g][1], accA[g], 0, 0, 0);
        }
    }

    int cur = 0;

#define STEP(ACCIN, ACCOUT, CT)                                                          \
    {                                                                                    \
        const int ct = (CT);                                                             \
        /* h A-frags (post-barrier critical path) */                                     \
        bfrag8 hf[4];                                                                    \
        _Pragma("unroll")                                                                \
        for (int k0 = 0; k0 < 4; ++k0)                                                   \
            hf[k0] = *(const bfrag8*)(&hbuf[cur][ln][k0 * 32 + qd * 8]);                 \
        /* x A-frags for t+1 (stable chunk buffer; ct==15 -> next chunk's buffer) */     \
        const int nbuf = (ct < CHK - 1) ? buf : (buf ^ 1);                               \
        const int nct  = (ct + 1) & (CHK - 1);                                           \
        bfrag8 xf0 = *(const bfrag8*)(&xs[nbuf][nct][ln & 7][qd * 8]);                   \
        bfrag8 xf1 = *(const bfrag8*)(&xs[nbuf][nct][ln & 7][32 + qd * 8]);              \
        /* h-part MFMAs into carried acc (which already holds bias + x(t)) */            \
        _Pragma("unroll")                                                                \
        for (int g = 0; g < 4; ++g)                                                      \
            _Pragma("unroll")                                                            \
            for (int k0 = 0; k0 < 4; ++k0)                                               \
                ACCIN[g] = __builtin_amdgcn_mfma_f32_16x16x32_bf16(hf[k0], whh[g][k0], ACCIN[g], 0, 0, 0); \
        /* exchange r2,r3 across 32-lane halves: every lane gets 2 valid units */        \
        float rc2[4], rc3[4];                                                            \
        _Pragma("unroll")                                                                \
        for (int g = 0; g < 4; ++g) {                                                    \
            rc2[g] = __shfl_xor(ACCIN[g][2], 32);                                        \
            rc3[g] = __shfl_xor(ACCIN[g][3], 32);                                        \
        }                                                                                \
        /* next step's x-part: fills MFMA pipe during cell phase */                      \
        _Pragma("unroll")                                                                \
        for (int g = 0; g < 4; ++g) {                                                    \
            ACCOUT[g] = (facc4){biasv[g], biasv[g], biasv[g], biasv[g]};                 \
            ACCOUT[g] = __builtin_amdgcn_mfma_f32_16x16x32_bf16(xf0, wih[g][0], ACCOUT[g], 0, 0, 0); \
            ACCOUT[g] = __builtin_amdgcn_mfma_f32_16x16x32_bf16(xf1, wih[g][1], ACCOUT[g], 0, 0, 0); \
        }                                                                                \
        if (ct == 0 && more) {      /* issue next chunk's global loads */                \
            const float* p = xsrc + (chunk + 1) * (CHK * DIN);                           \
            l0 = ((const float4*)p)[0];                                                  \
            l1 = ((const float4*)p)[1];                                                  \
            l2 = ((const float4*)p)[2];                                                  \
            l3 = ((const float4*)p)[3];                                                  \
        }                                                                                \
        if (ct == 12 && more) {     /* convert + write next chunk to LDS */              \
            bfrag8 o0, o1;                                                               \
            _Pragma("unroll")                                                            \
            for (int j = 0; j < 4; ++j) { o0[j] = f2bf(((float*)&l0)[j]); o0[4+j] = f2bf(((float*)&l1)[j]); } \
            _Pragma("unroll")                                                            \
            for (int j = 0; j < 4; ++j) { o1[j] = f2bf(((float*)&l2)[j]); o1[4+j] = f2bf(((float*)&l3)[j]); } \
            *(bfrag8*)&xs[buf ^ 1][stt][w][sdd]     = o0;                                \
            *(bfrag8*)&xs[buf ^ 1][stt][w][sdd + 8] = o1;                                \
        }                                                                                \
        /* LSTM cell on this lane's 2 assigned (seq, hid) units */                       \
        short hb[2];                                                                     \
        _Pragma("unroll")                                                                \
        for (int j = 0; j < 2; ++j) {                                                    \
            float u0 = hi ? (j ? rc3[0] : rc2[0]) : ACCIN[0][j];                         \
            float u1 = hi ? (j ? rc3[1] : rc2[1]) : ACCIN[1][j];                         \
            float u2 = hi ? (j ? rc3[2] : rc2[2]) : ACCIN[2][j];                         \
            float u3 = hi ? (j ? rc3[3] : rc2[3]) : ACCIN[3][j];                         \
            float iv = fast_sigmoid(u0);                                                 \
            float fv = fast_sigmoid(u1);                                                 \
            float gv = fast_tanh(u2);                                                    \
            float ov = fast_sigmoid(u3);                                                 \
            float c  = fv * cst[j] + iv * gv;                                            \
            cst[j]   = c;                                                                \
            float hv = ov * fast_tanh(c);                                                \
            hsum[j] += hv;                                                               \
            hb[j]    = f2bf(hv);                                                         \
        }                                                                                \
        ((short*)&hbuf[cur ^ 1][sq0][0])[khid] = hb[0];                                  \
        ((short*)&hbuf[cur ^ 1][sq1][0])[khid] = hb[1];                                  \
        __syncthreads();                                                                 \
        cur ^= 1;                                                                        \
    }

    for (int chunk = 0; chunk < LSEQ / CHK; ++chunk) {
        const int buf = chunk & 1;
        const bool more = chunk < (LSEQ / CHK - 1);
        float4 l0, l1, l2, l3;
#pragma unroll 1
        for (int ct2 = 0; ct2 < CHK / 2; ++ct2) {
            STEP(accA, accB, 2 * ct2);
            STEP(accB, accA, 2 * ct2 + 1);
        }
    }
#undef STEP

    // rep[b][k] = sum_t h_t[b][k] — every lane writes its 2 assigned seqs
    rep[(size_t)(s0 + sq0) * HID + khid] = hsum[0];
    rep[(size_t)(s0 + sq1) * HID + khid] = hsum[1];
}

// Epilogue: graph mean over C=32, classifier [10,128], log-softmax -> f32 out[64][10]
__global__ __launch_bounds__(128) void cls_kernel(
    const float* __restrict__ rep,    // [2048][128]
    const float* __restrict__ Wcls,   // [10][128]
    const float* __restrict__ bcls,   // [10]
    float* __restrict__ out)          // [64][10]
{
    __shared__ float m_s[HID];
    __shared__ float logits_s[NCLS];
    const int g = blockIdx.x;
    const int h = threadIdx.x;

    float s = 0.f;
#pragma unroll 4
    for (int c = 0; c < 32; ++c)
        s += rep[((size_t)g * 32 + c) * HID + h];
    m_s[h] = s * (1.0f / 32.0f);
    __syncthreads();

    if (h < NCLS) {
        float acc = bcls[h];
        for (int k = 0; k < HID; ++k)
            acc += m_s[k] * Wcls[h * HID + k];
        logits_s[h] = acc;
    }
    __syncthreads();

    if (h < NCLS) {
        float mx = logits_s[0];
#pragma unroll
        for (int j = 1; j < NCLS; ++j) mx = fmaxf(mx, logits_s[j]);
        float se = 0.f;
#pragma unroll
        for (int j = 0; j < NCLS; ++j)
            se += __builtin_amdgcn_exp2f((logits_s[j] - mx) * 1.4426950408889634f);
        float lse = mx + 0.6931471805599453f * __builtin_amdgcn_logf(se);
        out[g * NCLS + h] = logits_s[h] - lse;
    }
}

extern "C" void kernel_launch(void* const* d_in, const int* in_sizes, int n_in,
                              void* d_out, int out_size, void* d_ws, size_t ws_size,
                              hipStream_t stream) {
    const float* x    = (const float*)d_in[0];
    const float* Wih  = (const float*)d_in[1];
    const float* Whh  = (const float*)d_in[2];
    const float* bih  = (const float*)d_in[3];
    const float* bhh  = (const float*)d_in[4];
    const float* Wcls = (const float*)d_in[5];
    const float* bcls = (const float*)d_in[6];

    float* rep = (float*)d_ws;   // 2048*128 fp32 = 1 MB scratch

    lstm_fused<<<NSEQ / 8, 512, 0, stream>>>(x, Wih, Whh, bih, bhh, rep);
    cls_kernel<<<64, 128, 0, stream>>>(rep, Wcls, bcls, (float*)d_out);
}